// Round 3
// baseline (777.213 us; speedup 1.0000x reference)
//
#include <hip/hip_runtime.h>

#define NN 2048
#define HH 256
#define RR 22
#define EE 20000

typedef unsigned short u16;
typedef unsigned int   u32;
typedef __bf16 bf16x8 __attribute__((ext_vector_type(8)));
typedef float  f32x16 __attribute__((ext_vector_type(16)));

#define LDST 264   /* LDS row stride in bf16 elems: 256+8 pad */

__device__ __forceinline__ u16 f2bf(float f){
  union{float f; u32 u;} v; v.f = f; u32 u = v.u;
  return (u16)((u + 0x7FFFu + ((u>>16)&1u)) >> 16);
}

// ---- CSR build ------------------------------------------------------------
__global__ void count_k(const int* __restrict__ ei, int* __restrict__ cnt){
  int idx = blockIdx.x*256 + threadIdx.x;
  if (idx >= RR*EE) return;
  int r = idx / EE, e = idx - r*EE;
  int dst = ei[(r*2+1)*EE + e];
  atomicAdd(&cnt[r*NN + dst], 1);
}

__global__ void scan_k(const int* __restrict__ cnt, int* __restrict__ offs,
                       int* __restrict__ cursor){
  int r = blockIdx.x, t = threadIdx.x;   // 22 blocks x 256 threads
  __shared__ int part[256];
  int base = r*NN;
  int loc[8]; int s = 0;
  #pragma unroll
  for (int u=0; u<8; u++){ loc[u] = cnt[base + t*8 + u]; s += loc[u]; }
  part[t] = s;
  __syncthreads();
  for (int off=1; off<256; off<<=1){
    int v = (t>=off) ? part[t-off] : 0;
    __syncthreads();
    part[t] += v;
    __syncthreads();
  }
  int run = r*EE + part[t] - s;   // per-relation base + exclusive prefix
  #pragma unroll
  for (int u=0; u<8; u++){
    offs[base + t*8+u]   = run;
    cursor[base + t*8+u] = run;
    run += loc[u];
  }
}

__global__ void scatter_k(const int* __restrict__ ei, int* __restrict__ cursor,
                          int* __restrict__ csr){
  int idx = blockIdx.x*256 + threadIdx.x;
  if (idx >= RR*EE) return;
  int r = idx / EE, e = idx - r*EE;
  int src = ei[(r*2+0)*EE + e];
  int dst = ei[(r*2+1)*EE + e];
  int pos = atomicAdd(&cursor[r*NN + dst], 1);
  csr[pos] = src;
}

// ---- per-layer: Bt bf16 [23][256][256]; plane r<22 = Wl[l][r], plane 22 = sum_r Wr[l][r]
//      bias[o] = sum_r bl[l][r][o]
__global__ void convW_k(const float* __restrict__ Wl, const float* __restrict__ Wr,
                        const float* __restrict__ bl, int l,
                        u16* __restrict__ Bt, float* __restrict__ bias){
  int idx = blockIdx.x*256 + threadIdx.x;   // grid = 23*65536/256
  int plane = idx >> 16, rem = idx & 65535;
  if (plane < RR){
    Bt[idx] = f2bf(Wl[((size_t)l*RR + plane)*65536 + rem]);
  } else {
    float s = 0.f;
    for (int r=0;r<RR;r++) s += Wr[((size_t)l*RR + r)*65536 + rem];
    Bt[idx] = f2bf(s);
  }
  if (idx < HH){
    float b = 0.f;
    for (int r=0;r<RR;r++) b += bl[((size_t)l*RR + r)*HH + idx];
    bias[idx] = b;
  }
}

// ---- fused: gather-mean (fp32) -> bf16 LDS tile -> 32x32x16 MFMA -> atomic C
// grid (NN/32, RR+1); block 256 (4 waves). plane==RR is the root term.
__global__ void __launch_bounds__(256) fgemm_k(
    const float* __restrict__ xin, const int* __restrict__ offs,
    const int* __restrict__ cnt, const int* __restrict__ csr,
    const u16* __restrict__ Bt, float* __restrict__ C)
{
  __shared__ u16 At[32][LDST];
  int m0    = blockIdx.x * 32;
  int plane = blockIdx.y;          // 0..22
  int wid   = threadIdx.x >> 6;
  int lane  = threadIdx.x & 63;
  int c0    = lane * 4;

  // Phase 1: build 32x256 bf16 A tile in LDS (whole wave walks one row's edges)
  if (plane < RR){
    for (int rr = wid*8; rr < wid*8+8; rr++){
      int n = m0 + rr;
      int off = offs[plane*NN + n], deg = cnt[plane*NN + n];
      float a0=0.f,a1=0.f,a2=0.f,a3=0.f;
      for (int e = off; e < off + deg; e++){
        int s = csr[e];
        float4 v = *(const float4*)(xin + (size_t)s*HH + c0);
        a0 += v.x; a1 += v.y; a2 += v.z; a3 += v.w;
      }
      float inv = 1.0f / fmaxf((float)deg, 1.0f);
      ushort4 st; st.x=f2bf(a0*inv); st.y=f2bf(a1*inv); st.z=f2bf(a2*inv); st.w=f2bf(a3*inv);
      *(ushort4*)(&At[rr][c0]) = st;
    }
  } else {
    for (int rr = wid*8; rr < wid*8+8; rr++){
      float4 v = *(const float4*)(xin + (size_t)(m0+rr)*HH + c0);
      ushort4 st; st.x=f2bf(v.x); st.y=f2bf(v.y); st.z=f2bf(v.z); st.w=f2bf(v.w);
      *(ushort4*)(&At[rr][c0]) = st;
    }
  }
  __syncthreads();

  // Phase 2: wave wid -> output cols [wid*64, wid*64+64) as two 32-col MFMA tiles
  const u16* B = Bt + (size_t)plane*65536;   // B[o][i] bf16, row-major = B^T frag layout
  int colA  = wid*64 + (lane & 31);
  int colB  = colA + 32;
  int khalf = (lane >> 5) * 8;
  int arow  = lane & 31;
  f32x16 acc0, acc1;
  #pragma unroll
  for (int i=0;i<16;i++){ acc0[i]=0.f; acc1[i]=0.f; }
  #pragma unroll
  for (int kk = 0; kk < HH; kk += 16){
    bf16x8 af = *(const bf16x8*)(&At[arow][kk + khalf]);
    bf16x8 b0 = *(const bf16x8*)(B + (size_t)colA*HH + kk + khalf);
    bf16x8 b1 = *(const bf16x8*)(B + (size_t)colB*HH + kk + khalf);
    acc0 = __builtin_amdgcn_mfma_f32_32x32x16_bf16(af, b0, acc0, 0, 0, 0);
    acc1 = __builtin_amdgcn_mfma_f32_32x32x16_bf16(af, b1, acc1, 0, 0, 0);
  }
  #pragma unroll
  for (int reg=0; reg<16; reg++){
    int row = m0 + (reg&3) + 8*(reg>>2) + 4*(lane>>5);
    atomicAdd(&C[(size_t)row*HH + colA], acc0[reg]);
    atomicAdd(&C[(size_t)row*HH + colB], acc1[reg]);
  }
}

__global__ void epi_k(const float* __restrict__ C, const float* __restrict__ bias,
                      float* __restrict__ xo){
  int idx = blockIdx.x*256 + threadIdx.x;   // NN*HH exact
  int o = idx & 255;
  xo[idx] = fmaxf(C[idx] + bias[o], 0.f);
}

// ---- coefficients: m[n][r], p[n][r] = m*a ---------------------------------
__global__ void coeff_k(const float* __restrict__ x2, const float* __restrict__ Wa,
                        const float* __restrict__ ba, const float* __restrict__ Wm,
                        const float* __restrict__ bm,
                        float* __restrict__ mbuf, float* __restrict__ pbuf){
  int idx = blockIdx.x*256 + threadIdx.x;   // NN*RR = 45056 exact
  int n = idx / RR, r = idx - n*RR;
  const float4* xr = (const float4*)(x2 + (size_t)n*HH);
  const float4* wa = (const float4*)(Wa + (size_t)r*HH);
  const float4* wm = (const float4*)(Wm + (size_t)r*HH);
  float da=0.f, dm=0.f;
  #pragma unroll 4
  for (int h=0; h<HH/4; h++){
    float4 xv = xr[h], av = wa[h], mv = wm[h];
    da += xv.x*av.x + xv.y*av.y + xv.z*av.z + xv.w*av.w;
    dm += xv.x*mv.x + xv.y*mv.y + xv.z*mv.z + xv.w*mv.w;
  }
  float a = fmaxf(da + ba[r], 0.f);
  float m = fmaxf(dm + bm[r], 0.f);
  mbuf[idx] = m;
  pbuf[idx] = m*a;
}

// ---- final: out[i,j] = sum_r m[i,r]*adj[i,j,r] + sum_r m[i,r]*a[i,r] ------
__global__ void final_k(const float* __restrict__ adj, const float* __restrict__ mbuf,
                        const float* __restrict__ pbuf, float* __restrict__ out){
  int i = blockIdx.y;
  int j = blockIdx.x*256 + threadIdx.x;
  float mv[RR];
  float s = 0.f;
  #pragma unroll
  for (int r=0;r<RR;r++){ mv[r] = mbuf[i*RR+r]; s += pbuf[i*RR+r]; }
  const float2* ap = (const float2*)(adj + ((size_t)i*NN + j)*RR);  // 88B row, 8-aligned
  float acc = s;
  #pragma unroll
  for (int k=0;k<RR/2;k++){
    float2 w = ap[k];
    acc += mv[2*k]*w.x + mv[2*k+1]*w.y;
  }
  out[(size_t)i*NN + j] = acc;
}

extern "C" void kernel_launch(void* const* d_in, const int* in_sizes, int n_in,
                              void* d_out, int out_size, void* d_ws, size_t ws_size,
                              hipStream_t stream) {
  const float* x0  = (const float*)d_in[0];
  const float* adj = (const float*)d_in[1];
  const float* Wl  = (const float*)d_in[2];
  const float* bl  = (const float*)d_in[3];
  const float* Wr  = (const float*)d_in[4];
  const float* Wa  = (const float*)d_in[5];
  const float* ba  = (const float*)d_in[6];
  const float* Wm  = (const float*)d_in[7];
  const float* bm  = (const float*)d_in[8];
  const int*   ei  = (const int*)d_in[9];
  float* out = (float*)d_out;

  char* w = (char*)d_ws;
  auto alloc = [&](size_t bytes){ char* p = w; w += (bytes + 255) & ~255ull; return p; };
  int*   cnt    = (int*)  alloc((size_t)RR*NN*4);
  int*   offs   = (int*)  alloc((size_t)RR*NN*4);
  int*   cursor = (int*)  alloc((size_t)RR*NN*4);
  int*   csr    = (int*)  alloc((size_t)RR*EE*4);
  u16*   Bt     = (u16*)  alloc((size_t)(RR+1)*HH*HH*2);
  float* bias   = (float*)alloc((size_t)HH*4);
  float* C      = (float*)alloc((size_t)NN*HH*4);
  float* x1     = (float*)alloc((size_t)NN*HH*4);
  float* mbuf   = (float*)alloc((size_t)NN*RR*4);
  float* pbuf   = (float*)alloc((size_t)NN*RR*4);
  // total ~9.6 MB

  hipMemsetAsync(cnt, 0, (size_t)RR*NN*4, stream);
  count_k  <<<(RR*EE+255)/256, 256, 0, stream>>>(ei, cnt);
  scan_k   <<<RR, 256, 0, stream>>>(cnt, offs, cursor);
  scatter_k<<<(RR*EE+255)/256, 256, 0, stream>>>(ei, cursor, csr);

  const float* xcur = x0;
  for (int l=0; l<2; l++){
    convW_k<<<((RR+1)*HH*HH)/256, 256, 0, stream>>>(Wl, Wr, bl, l, Bt, bias);
    hipMemsetAsync(C, 0, (size_t)NN*HH*4, stream);
    fgemm_k<<<dim3(NN/32, RR+1), 256, 0, stream>>>(xcur, offs, cnt, csr, Bt, C);
    epi_k  <<<(NN*HH)/256, 256, 0, stream>>>(C, bias, x1);
    xcur = x1;
  }

  coeff_k<<<(NN*RR)/256, 256, 0, stream>>>(x1, Wa, ba, Wm, bm, mbuf, pbuf);
  final_k<<<dim3(NN/256, NN), 256, 0, stream>>>(adj, mbuf, pbuf, out);
}

// Round 4
// 770.460 us; speedup vs baseline: 1.0088x; 1.0088x over previous
//
#include <hip/hip_runtime.h>

#define NN 2048
#define HH 256
#define RR 22
#define EE 20000

typedef unsigned short u16;
typedef unsigned int   u32;
typedef __bf16 bf16x8 __attribute__((ext_vector_type(8)));
typedef float  f32x16 __attribute__((ext_vector_type(16)));

#define LDST 264   /* LDS row stride in bf16 elems: 256+8 pad */

__device__ __forceinline__ u16 f2bf(float f){
  union{float f; u32 u;} v; v.f = f; u32 u = v.u;
  return (u16)((u + 0x7FFFu + ((u>>16)&1u)) >> 16);
}

// ---- CSR build ------------------------------------------------------------
__global__ void count_k(const int* __restrict__ ei, int* __restrict__ cnt){
  int idx = blockIdx.x*256 + threadIdx.x;
  if (idx >= RR*EE) return;
  int r = idx / EE, e = idx - r*EE;
  int dst = ei[(r*2+1)*EE + e];
  atomicAdd(&cnt[r*NN + dst], 1);
}

__global__ void scan_k(const int* __restrict__ cnt, int* __restrict__ offs,
                       int* __restrict__ cursor){
  int r = blockIdx.x, t = threadIdx.x;   // 22 blocks x 256 threads
  __shared__ int part[256];
  int base = r*NN;
  int loc[8]; int s = 0;
  #pragma unroll
  for (int u=0; u<8; u++){ loc[u] = cnt[base + t*8 + u]; s += loc[u]; }
  part[t] = s;
  __syncthreads();
  for (int off=1; off<256; off<<=1){
    int v = (t>=off) ? part[t-off] : 0;
    __syncthreads();
    part[t] += v;
    __syncthreads();
  }
  int run = r*EE + part[t] - s;   // per-relation base + exclusive prefix
  #pragma unroll
  for (int u=0; u<8; u++){
    offs[base + t*8+u]   = run;
    cursor[base + t*8+u] = run;
    run += loc[u];
  }
}

__global__ void scatter_k(const int* __restrict__ ei, int* __restrict__ cursor,
                          int* __restrict__ csr){
  int idx = blockIdx.x*256 + threadIdx.x;
  if (idx >= RR*EE) return;
  int r = idx / EE, e = idx - r*EE;
  int src = ei[(r*2+0)*EE + e];
  int dst = ei[(r*2+1)*EE + e];
  int pos = atomicAdd(&cursor[r*NN + dst], 1);
  csr[pos] = src;
}

// ---- per-layer: Bt bf16 [23][256][256]; plane r<22 = Wl[l][r], plane 22 = sum_r Wr[l][r]
//      bias[o] = sum_r bl[l][r][o]
__global__ void convW_k(const float* __restrict__ Wl, const float* __restrict__ Wr,
                        const float* __restrict__ bl, int l,
                        u16* __restrict__ Bt, float* __restrict__ bias){
  int idx = blockIdx.x*256 + threadIdx.x;   // grid = 23*65536/256
  int plane = idx >> 16, rem = idx & 65535;
  if (plane < RR){
    Bt[idx] = f2bf(Wl[((size_t)l*RR + plane)*65536 + rem]);
  } else {
    float s = 0.f;
    for (int r=0;r<RR;r++) s += Wr[((size_t)l*RR + r)*65536 + rem];
    Bt[idx] = f2bf(s);
  }
  if (idx < HH){
    float b = 0.f;
    for (int r=0;r<RR;r++) b += bl[((size_t)l*RR + r)*HH + idx];
    bias[idx] = b;
  }
}

// ---- fused: gather-mean (fp32) -> bf16 LDS tile -> 32x32x16 MFMA -> Cp store
// grid (NN/32, RR+1); block 256 (4 waves). plane==RR is the root term.
// Writes per-plane partials Cp[plane][n][o] — NO atomics (round-3 had 12M
// 23-way-contended atomicAdds here; theory: that was ~400us of the 777).
__global__ void __launch_bounds__(256) fgemm_k(
    const float* __restrict__ xin, const int* __restrict__ offs,
    const int* __restrict__ cnt, const int* __restrict__ csr,
    const u16* __restrict__ Bt, float* __restrict__ Cp)
{
  __shared__ u16 At[32][LDST];
  int m0    = blockIdx.x * 32;
  int plane = blockIdx.y;          // 0..22
  int wid   = threadIdx.x >> 6;
  int lane  = threadIdx.x & 63;
  int c0    = lane * 4;

  // Phase 1: build 32x256 bf16 A tile in LDS (whole wave walks one row's edges)
  if (plane < RR){
    for (int rr = wid*8; rr < wid*8+8; rr++){
      int n = m0 + rr;
      int off = offs[plane*NN + n], deg = cnt[plane*NN + n];
      float a0=0.f,a1=0.f,a2=0.f,a3=0.f;
      for (int e = off; e < off + deg; e++){
        int s = csr[e];
        float4 v = *(const float4*)(xin + (size_t)s*HH + c0);
        a0 += v.x; a1 += v.y; a2 += v.z; a3 += v.w;
      }
      float inv = 1.0f / fmaxf((float)deg, 1.0f);
      ushort4 st; st.x=f2bf(a0*inv); st.y=f2bf(a1*inv); st.z=f2bf(a2*inv); st.w=f2bf(a3*inv);
      *(ushort4*)(&At[rr][c0]) = st;
    }
  } else {
    for (int rr = wid*8; rr < wid*8+8; rr++){
      float4 v = *(const float4*)(xin + (size_t)(m0+rr)*HH + c0);
      ushort4 st; st.x=f2bf(v.x); st.y=f2bf(v.y); st.z=f2bf(v.z); st.w=f2bf(v.w);
      *(ushort4*)(&At[rr][c0]) = st;
    }
  }
  __syncthreads();

  // Phase 2: wave wid -> output cols [wid*64, wid*64+64) as two 32-col MFMA tiles
  const u16* B = Bt + (size_t)plane*65536;   // B[o][i] bf16, row-major = B^T frag layout
  int colA  = wid*64 + (lane & 31);
  int colB  = colA + 32;
  int khalf = (lane >> 5) * 8;
  int arow  = lane & 31;
  f32x16 acc0, acc1;
  #pragma unroll
  for (int i=0;i<16;i++){ acc0[i]=0.f; acc1[i]=0.f; }
  #pragma unroll
  for (int kk = 0; kk < HH; kk += 16){
    bf16x8 af = *(const bf16x8*)(&At[arow][kk + khalf]);
    bf16x8 b0 = *(const bf16x8*)(B + (size_t)colA*HH + kk + khalf);
    bf16x8 b1 = *(const bf16x8*)(B + (size_t)colB*HH + kk + khalf);
    acc0 = __builtin_amdgcn_mfma_f32_32x32x16_bf16(af, b0, acc0, 0, 0, 0);
    acc1 = __builtin_amdgcn_mfma_f32_32x32x16_bf16(af, b1, acc1, 0, 0, 0);
  }
  float* Cpl = Cp + (size_t)plane*NN*HH;
  #pragma unroll
  for (int reg=0; reg<16; reg++){
    int row = m0 + (reg&3) + 8*(reg>>2) + 4*(lane>>5);
    Cpl[(size_t)row*HH + colA] = acc0[reg];
    Cpl[(size_t)row*HH + colB] = acc1[reg];
  }
}

// ---- reduce 23 planes + bias + relu -> x1 ---------------------------------
__global__ void red_k(const float* __restrict__ Cp, const float* __restrict__ bias,
                      float* __restrict__ xo){
  int idx = blockIdx.x*256 + threadIdx.x;   // NN*HH exact
  int o = idx & 255;
  float s = bias[o];
  #pragma unroll
  for (int p=0; p<RR+1; p++) s += Cp[(size_t)p*NN*HH + idx];
  xo[idx] = fmaxf(s, 0.f);
}

// ---- coefficients: m[n][r], p[n][r] = m*a ---------------------------------
__global__ void coeff_k(const float* __restrict__ x2, const float* __restrict__ Wa,
                        const float* __restrict__ ba, const float* __restrict__ Wm,
                        const float* __restrict__ bm,
                        float* __restrict__ mbuf, float* __restrict__ pbuf){
  int idx = blockIdx.x*256 + threadIdx.x;   // NN*RR = 45056 exact
  int n = idx / RR, r = idx - n*RR;
  const float4* xr = (const float4*)(x2 + (size_t)n*HH);
  const float4* wa = (const float4*)(Wa + (size_t)r*HH);
  const float4* wm = (const float4*)(Wm + (size_t)r*HH);
  float da=0.f, dm=0.f;
  #pragma unroll 4
  for (int h=0; h<HH/4; h++){
    float4 xv = xr[h], av = wa[h], mv = wm[h];
    da += xv.x*av.x + xv.y*av.y + xv.z*av.z + xv.w*av.w;
    dm += xv.x*mv.x + xv.y*mv.y + xv.z*mv.z + xv.w*mv.w;
  }
  float a = fmaxf(da + ba[r], 0.f);
  float m = fmaxf(dm + bm[r], 0.f);
  mbuf[idx] = m;
  pbuf[idx] = m*a;
}

// ---- final: out[i,j] = sum_r m[i,r]*adj[i,j,r] + sum_r m[i,r]*a[i,r] ------
__global__ void final_k(const float* __restrict__ adj, const float* __restrict__ mbuf,
                        const float* __restrict__ pbuf, float* __restrict__ out){
  int i = blockIdx.y;
  int j = blockIdx.x*256 + threadIdx.x;
  float mv[RR];
  float s = 0.f;
  #pragma unroll
  for (int r=0;r<RR;r++){ mv[r] = mbuf[i*RR+r]; s += pbuf[i*RR+r]; }
  const float2* ap = (const float2*)(adj + ((size_t)i*NN + j)*RR);  // 88B row, 8-aligned
  float acc = s;
  #pragma unroll
  for (int k=0;k<RR/2;k++){
    float2 w = ap[k];
    acc += mv[2*k]*w.x + mv[2*k+1]*w.y;
  }
  out[(size_t)i*NN + j] = acc;
}

extern "C" void kernel_launch(void* const* d_in, const int* in_sizes, int n_in,
                              void* d_out, int out_size, void* d_ws, size_t ws_size,
                              hipStream_t stream) {
  const float* x0  = (const float*)d_in[0];
  const float* adj = (const float*)d_in[1];
  const float* Wl  = (const float*)d_in[2];
  const float* bl  = (const float*)d_in[3];
  const float* Wr  = (const float*)d_in[4];
  const float* Wa  = (const float*)d_in[5];
  const float* ba  = (const float*)d_in[6];
  const float* Wm  = (const float*)d_in[7];
  const float* bm  = (const float*)d_in[8];
  const int*   ei  = (const int*)d_in[9];
  float* out = (float*)d_out;

  char* w = (char*)d_ws;
  auto alloc = [&](size_t bytes){ char* p = w; w += (bytes + 255) & ~255ull; return p; };
  int*   cnt    = (int*)  alloc((size_t)RR*NN*4);
  int*   offs   = (int*)  alloc((size_t)RR*NN*4);
  int*   cursor = (int*)  alloc((size_t)RR*NN*4);
  int*   csr    = (int*)  alloc((size_t)RR*EE*4);
  u16*   Bt     = (u16*)  alloc((size_t)(RR+1)*HH*HH*2);
  float* bias   = (float*)alloc((size_t)HH*4);
  float* Cp     = (float*)alloc((size_t)(RR+1)*NN*HH*4);  // 48 MB partials (ws ~1.5 GB)
  float* x1     = (float*)alloc((size_t)NN*HH*4);
  float* mbuf   = (float*)alloc((size_t)NN*RR*4);
  float* pbuf   = (float*)alloc((size_t)NN*RR*4);

  hipMemsetAsync(cnt, 0, (size_t)RR*NN*4, stream);
  count_k  <<<(RR*EE+255)/256, 256, 0, stream>>>(ei, cnt);
  scan_k   <<<RR, 256, 0, stream>>>(cnt, offs, cursor);
  scatter_k<<<(RR*EE+255)/256, 256, 0, stream>>>(ei, cursor, csr);

  const float* xcur = x0;
  for (int l=0; l<2; l++){
    convW_k<<<((RR+1)*HH*HH)/256, 256, 0, stream>>>(Wl, Wr, bl, l, Bt, bias);
    fgemm_k<<<dim3(NN/32, RR+1), 256, 0, stream>>>(xcur, offs, cnt, csr, Bt, Cp);
    red_k  <<<(NN*HH)/256, 256, 0, stream>>>(Cp, bias, x1);
    xcur = x1;
  }

  coeff_k<<<(NN*RR)/256, 256, 0, stream>>>(x1, Wa, ba, Wm, bm, mbuf, pbuf);
  final_k<<<dim3(NN/256, NN), 256, 0, stream>>>(adj, mbuf, pbuf, out);
}